// Round 8
// baseline (293.182 us; speedup 1.0000x reference)
//
#include <hip/hip_runtime.h>
#include <hip/hip_bf16.h>
#include <math.h>

#define S_LEN 2048
#define HID   1024
#define NHEAD 16

using bf16x8 = __attribute__((ext_vector_type(8))) short;
using f32x4  = __attribute__((ext_vector_type(4))) float;

__device__ __forceinline__ float bf2f(short s) {
  union { unsigned u; float f; } c;
  c.u = ((unsigned)(unsigned short)s) << 16;
  return c.f;
}
__device__ __forceinline__ short f2bf(float f) {
  union { float f; unsigned u; } c; c.f = f;
  unsigned u = c.u;
  unsigned r = (u + 0x7fffu + ((u >> 16) & 1u)) >> 16;
  return (short)r;
}
__device__ __forceinline__ bf16x8 load8(const void* base, long idx, int is_bf) {
  if (is_bf) return *(const bf16x8*)((const short*)base + idx);
  const float* p = (const float*)base + idx;
  bf16x8 r;
#pragma unroll
  for (int j = 0; j < 8; ++j) r[j] = f2bf(p[j]);
  return r;
}
__device__ __forceinline__ float loadf(const void* base, long idx, int is_bf) {
  return is_bf ? bf2f(((const short*)base)[idx]) : ((const float*)base)[idx];
}

// flags[0]=1 iff float arrays are packed bf16; 0 if fp32 storage.
// flags[1]=1 iff modality_info is int64.
__global__ void detect_kernel(const unsigned* __restrict__ xw,
                              const int* __restrict__ modw,
                              int* __restrict__ flags) {
  const int t = threadIdx.x;  // 64 threads
  int cnt = 0;
  for (int i = t; i < 1024; i += 64) {
    const unsigned fld = (xw[i] >> 7) & 0xFFu;
    cnt += (fld >= 100u && fld <= 135u) ? 1 : 0;
  }
  int odd = 0;
  for (int i = 0; i < 4; ++i) {
    const int wv = modw[2 * (t + 64 * i) + 1];
    odd += (wv != 0) ? 1 : 0;
  }
  for (int m = 1; m < 64; m <<= 1) {
    cnt += __shfl_xor(cnt, m);
    odd += __shfl_xor(odd, m);
  }
  if (t == 0) {
    flags[0] = (cnt >= 512) ? 1 : 0;
    flags[1] = (odd == 0) ? 1 : 0;
  }
}

// C[m,n] = A[m,:] . W[n,:] + bias[n]  (B^T GEMM, fp32 acc).
// A dtype: a_force_bf ? bf16 : flags[0]. W/bias dtype: flags[0].
// Output: store_f32 ? float : bf16.   M=2048, K=N=1024 per matrix.
__global__ __launch_bounds__(256) void gemm_bt3(
    const void* __restrict__ A,
    const void* __restrict__ W0, const void* __restrict__ W1, const void* __restrict__ W2,
    const void* __restrict__ b0, const void* __restrict__ b1, const void* __restrict__ b2,
    void* __restrict__ C0, void* __restrict__ C1, void* __restrict__ C2,
    const int* __restrict__ flags, int nbn, int a_force_bf, int store_f32)
{
  constexpr int K = 1024;
  constexpr int N = 1024;
  __shared__ short As[128 * 32];
  __shared__ short Bs[128 * 32];

  const int t = threadIdx.x;
  const int w = t >> 6, lane = t & 63;
  const int l15 = lane & 15, quad = lane >> 4;
  const int wm = w >> 1, wn = w & 1;

  const int is_bf = flags[0];
  const int a_bf = a_force_bf ? 1 : is_bf;

  const int bx = blockIdx.x;
  const int mat = bx / nbn;
  const int n0 = (bx % nbn) * 128;
  const int m0 = blockIdx.y * 128;

  const void* W   = (mat == 0) ? W0 : (mat == 1 ? W1 : W2);
  const void* bia = (mat == 0) ? b0 : (mat == 1 ? b1 : b2);
  void*       C   = (mat == 0) ? C0 : (mat == 1 ? C1 : C2);

  f32x4 acc[4][4];
  for (int mi = 0; mi < 4; ++mi)
    for (int ni = 0; ni < 4; ++ni)
      for (int r = 0; r < 4; ++r) acc[mi][ni][r] = 0.f;

  const int srow = t >> 2;
  const int sch  = (t & 3) * 8;
  const long aBase = (long)(m0 + srow) * K + sch;
  const long wBase = (long)(n0 + srow) * K + sch;

  for (int kt = 0; kt < K / 32; ++kt) {
    const bf16x8 ra0 = load8(A, aBase + kt * 32, a_bf);
    const bf16x8 ra1 = load8(A, aBase + kt * 32 + 64L * K, a_bf);
    const bf16x8 rb0 = load8(W, wBase + kt * 32, is_bf);
    const bf16x8 rb1 = load8(W, wBase + kt * 32 + 64L * K, is_bf);
    __syncthreads();
    *(bf16x8*)&As[(srow)      * 32 + sch] = ra0;
    *(bf16x8*)&As[(srow + 64) * 32 + sch] = ra1;
    *(bf16x8*)&Bs[(srow)      * 32 + sch] = rb0;
    *(bf16x8*)&Bs[(srow + 64) * 32 + sch] = rb1;
    __syncthreads();

    bf16x8 af[4], bfr[4];
    for (int mi = 0; mi < 4; ++mi)
      af[mi] = *(const bf16x8*)&As[(wm * 64 + mi * 16 + l15) * 32 + quad * 8];
    for (int ni = 0; ni < 4; ++ni)
      bfr[ni] = *(const bf16x8*)&Bs[(wn * 64 + ni * 16 + l15) * 32 + quad * 8];
    for (int mi = 0; mi < 4; ++mi)
      for (int ni = 0; ni < 4; ++ni)
        acc[mi][ni] = __builtin_amdgcn_mfma_f32_16x16x32_bf16(af[mi], bfr[ni], acc[mi][ni], 0, 0, 0);
  }

  for (int ni = 0; ni < 4; ++ni) {
    const int col = n0 + wn * 64 + ni * 16 + l15;
    const float bv = loadf(bia, col, is_bf);
    for (int mi = 0; mi < 4; ++mi) {
      const int row = m0 + wm * 64 + mi * 16 + quad * 4;
      for (int r = 0; r < 4; ++r) {
        const float v = acc[mi][ni][r] + bv;
        const long idx = (long)(row + r) * N + col;
        if (store_f32) ((float*)C)[idx] = v;
        else           ((short*)C)[idx] = f2bf(v);
      }
    }
  }
}

// Flash attention, causal, modality bias. Block = 64 Q rows (4 waves x 16 rows), one head.
// Q/K/V bf16 (from gemm_bt3). cmw dtype per flags[0]; modality per flags[1].
__global__ __launch_bounds__(256) void attn_kernel(
    const short* __restrict__ Q, const short* __restrict__ Kg, const short* __restrict__ Vg,
    const int* __restrict__ mod, const void* __restrict__ cmw,
    const int* __restrict__ flags, short* __restrict__ CTX)
{
  __shared__ short Ks[64 * 80];
  __shared__ short Vt[64 * 80];
  __shared__ short Ps[4 * 16 * 80];
  __shared__ float cm[9];

  const int t = threadIdx.x;
  const int w = t >> 6, lane = t & 63;
  const int l15 = lane & 15, quad = lane >> 4;
  const int h = blockIdx.y;
  const int q0 = blockIdx.x * 64;
  const int m64 = flags[1];

  if (t < 9) cm[t] = loadf(cmw, t, flags[0]);

  const int qrow_a = q0 + w * 16 + l15;
  const short* qb = Q + (long)qrow_a * HID + h * 64 + quad * 8;
  const bf16x8 aq0 = *(const bf16x8*)qb;
  const bf16x8 aq1 = *(const bf16x8*)(qb + 32);

  int mrow[4];
  for (int r = 0; r < 4; ++r) mrow[r] = mod[(q0 + w * 16 + quad * 4 + r) << m64];

  float m_i[4], l_i[4];
  f32x4 acc_o[4];
  for (int r = 0; r < 4; ++r) { m_i[r] = -1e30f; l_i[r] = 0.f; }
  for (int ni = 0; ni < 4; ++ni)
    for (int r = 0; r < 4; ++r) acc_o[ni][r] = 0.f;

  const int nkt = blockIdx.x + 1;
  for (int kt = 0; kt < nkt; ++kt) {
    __syncthreads();
    {
      int slot = t;
      for (int it = 0; it < 2; ++it, slot += 256) {
        const int row = slot >> 3, ch = (slot & 7) * 8;
        bf16x8 v = *(const bf16x8*)(Kg + (long)(kt * 64 + row) * HID + h * 64 + ch);
        *(bf16x8*)&Ks[row * 80 + ch] = v;
      }
      const int kp = t & 63, dc = (t >> 6) * 8;
      const short* vrow = Vg + (long)(kt * 64 + kp) * HID + h * 64;
      bf16x8 v0 = *(const bf16x8*)(vrow + dc);
      bf16x8 v1 = *(const bf16x8*)(vrow + 32 + dc);
      for (int j = 0; j < 8; ++j) Vt[(dc + j) * 80 + kp] = v0[j];
      for (int j = 0; j < 8; ++j) Vt[(dc + 32 + j) * 80 + kp] = v1[j];
    }
    __syncthreads();

    f32x4 sc[4];
    for (int nt = 0; nt < 4; ++nt) {
      const bf16x8 kb0 = *(const bf16x8*)&Ks[(nt * 16 + l15) * 80 + quad * 8];
      const bf16x8 kb1 = *(const bf16x8*)&Ks[(nt * 16 + l15) * 80 + 32 + quad * 8];
      f32x4 z;
      for (int r = 0; r < 4; ++r) z[r] = 0.f;
      z = __builtin_amdgcn_mfma_f32_16x16x32_bf16(aq0, kb0, z, 0, 0, 0);
      z = __builtin_amdgcn_mfma_f32_16x16x32_bf16(aq1, kb1, z, 0, 0, 0);
      sc[nt] = z;
    }

    int mcol[4];
    for (int nt = 0; nt < 4; ++nt) mcol[nt] = mod[(kt * 64 + nt * 16 + l15) << m64];
    float sv[4][4], rmax[4];
    for (int r = 0; r < 4; ++r) rmax[r] = -1e30f;
    for (int nt = 0; nt < 4; ++nt) {
      const int col = kt * 64 + nt * 16 + l15;
      for (int r = 0; r < 4; ++r) {
        const int row = q0 + w * 16 + quad * 4 + r;
        float x = sc[nt][r] * 0.125f + cm[mrow[r] * 3 + mcol[nt]];
        x = (col <= row) ? x : -1e30f;
        sv[nt][r] = x;
        rmax[r] = fmaxf(rmax[r], x);
      }
    }
    for (int off = 1; off < 16; off <<= 1)
      for (int r = 0; r < 4; ++r) rmax[r] = fmaxf(rmax[r], __shfl_xor(rmax[r], off));

    float alpha[4], rsum[4];
    for (int r = 0; r < 4; ++r) {
      const float mn = fmaxf(m_i[r], rmax[r]);
      alpha[r] = __expf(m_i[r] - mn);
      m_i[r] = mn;
      rsum[r] = 0.f;
    }
    short pb[4][4];
    for (int nt = 0; nt < 4; ++nt)
      for (int r = 0; r < 4; ++r) {
        const float p = __expf(sv[nt][r] - m_i[r]);
        rsum[r] += p;
        pb[nt][r] = f2bf(p);
      }
    for (int off = 1; off < 16; off <<= 1)
      for (int r = 0; r < 4; ++r) rsum[r] += __shfl_xor(rsum[r], off);
    for (int r = 0; r < 4; ++r) l_i[r] = l_i[r] * alpha[r] + rsum[r];
    for (int ni = 0; ni < 4; ++ni)
      for (int r = 0; r < 4; ++r) acc_o[ni][r] *= alpha[r];

    short* Pw = &Ps[w * 16 * 80];
    for (int nt = 0; nt < 4; ++nt)
      for (int r = 0; r < 4; ++r)
        Pw[(quad * 4 + r) * 80 + nt * 16 + l15] = pb[nt][r];
    __syncthreads();

    for (int kk = 0; kk < 2; ++kk) {
      const bf16x8 ap = *(const bf16x8*)&Pw[l15 * 80 + kk * 32 + quad * 8];
      for (int ni = 0; ni < 4; ++ni) {
        const bf16x8 bv = *(const bf16x8*)&Vt[(ni * 16 + l15) * 80 + kk * 32 + quad * 8];
        acc_o[ni] = __builtin_amdgcn_mfma_f32_16x16x32_bf16(ap, bv, acc_o[ni], 0, 0, 0);
      }
    }
  }

  for (int ni = 0; ni < 4; ++ni) {
    const int col = h * 64 + ni * 16 + l15;
    for (int r = 0; r < 4; ++r) {
      const int row = q0 + w * 16 + quad * 4 + r;
      CTX[(long)row * HID + col] = f2bf(acc_o[ni][r] / l_i[r]);
    }
  }
}

extern "C" void kernel_launch(void* const* d_in, const int* in_sizes, int n_in,
                              void* d_out, int out_size, void* d_ws, size_t ws_size,
                              hipStream_t stream) {
  constexpr long M1 = 1024L * 1024L;
  int*   flags = (int*)d_ws;
  short* base  = (short*)d_ws + 128;
  short* Qw  = base;                 // 2M shorts = 4MB each
  short* Kw  = Qw + 2 * M1;
  short* Vw  = Kw + 2 * M1;
  short* CTX = Vw + 2 * M1;          // ws use: 16MB + 256B
  const int* modality = (const int*)d_in[11];

  detect_kernel<<<1, 64, 0, stream>>>((const unsigned*)d_in[0], modality, flags);

  // QKV projection (MFMA): A=x, W=Wq/Wk/Wv -> bf16 Q/K/V in ws
  gemm_bt3<<<dim3(24, 16), 256, 0, stream>>>(
      d_in[0], d_in[1], d_in[3], d_in[5], d_in[2], d_in[4], d_in[6],
      Qw, Kw, Vw, flags, 8, /*a_force_bf=*/0, /*store_f32=*/0);
  // attention (flash, MFMA)
  attn_kernel<<<dim3(32, NHEAD), 256, 0, stream>>>(Qw, Kw, Vw, modality, d_in[9], flags, CTX);
  // output projection (MFMA): A=CTX bf16, W=Wo -> FP32 out (the round-7 fix)
  gemm_bt3<<<dim3(8, 16), 256, 0, stream>>>(
      CTX, d_in[7], d_in[7], d_in[7], d_in[8], d_in[8], d_in[8],
      d_out, d_out, d_out, flags, 8, /*a_force_bf=*/1, /*store_f32=*/1);
}

// Round 9
// 206.816 us; speedup vs baseline: 1.4176x; 1.4176x over previous
//
#include <hip/hip_runtime.h>
#include <hip/hip_bf16.h>
#include <math.h>

#define S_LEN 2048
#define HID   1024
#define NHEAD 16

using bf16x8 = __attribute__((ext_vector_type(8))) short;
using f32x4  = __attribute__((ext_vector_type(4))) float;

__device__ __forceinline__ float bf2f(short s) {
  union { unsigned u; float f; } c;
  c.u = ((unsigned)(unsigned short)s) << 16;
  return c.f;
}
__device__ __forceinline__ short f2bf(float f) {
  union { float f; unsigned u; } c; c.f = f;
  unsigned u = c.u;
  unsigned r = (u + 0x7fffu + ((u >> 16) & 1u)) >> 16;
  return (short)r;
}
__device__ __forceinline__ float loadf(const void* base, long idx, int is_bf) {
  return is_bf ? bf2f(((const short*)base)[idx]) : ((const float*)base)[idx];
}

// flags[0]=1 iff float arrays are packed bf16; 0 if fp32 storage.
// flags[1]=1 iff modality_info is int64.
__global__ void detect_kernel(const unsigned* __restrict__ xw,
                              const int* __restrict__ modw,
                              int* __restrict__ flags) {
  const int t = threadIdx.x;  // 64 threads
  int cnt = 0;
  for (int i = t; i < 1024; i += 64) {
    const unsigned fld = (xw[i] >> 7) & 0xFFu;
    cnt += (fld >= 100u && fld <= 135u) ? 1 : 0;
  }
  int odd = 0;
  for (int i = 0; i < 4; ++i) {
    const int wv = modw[2 * (t + 64 * i) + 1];
    odd += (wv != 0) ? 1 : 0;
  }
  for (int m = 1; m < 64; m <<= 1) {
    cnt += __shfl_xor(cnt, m);
    odd += __shfl_xor(odd, m);
  }
  if (t == 0) {
    flags[0] = (cnt >= 512) ? 1 : 0;
    flags[1] = (odd == 0) ? 1 : 0;
  }
}

// One launch converts x + 4 weight matrices to bf16 (or copies if already bf16).
// blockIdx.y selects array: 0=x (2M elems), 1..4 = W (1M each).
__global__ __launch_bounds__(256) void convert5(
    const void* __restrict__ s0, const void* __restrict__ s1, const void* __restrict__ s2,
    const void* __restrict__ s3, const void* __restrict__ s4,
    short* __restrict__ d0, short* __restrict__ d1, short* __restrict__ d2,
    short* __restrict__ d3, short* __restrict__ d4,
    const int* __restrict__ flags) {
  const int a = blockIdx.y;
  const void* src = (a == 0) ? s0 : (a == 1) ? s1 : (a == 2) ? s2 : (a == 3) ? s3 : s4;
  short* dst = (a == 0) ? d0 : (a == 1) ? d1 : (a == 2) ? d2 : (a == 3) ? d3 : d4;
  const long n = (a == 0) ? (2L << 20) : (1L << 20);
  const int is_bf = flags[0];
  long i = (long)(blockIdx.x * 256 + threadIdx.x) * 8;
  const long stride = (long)gridDim.x * 256 * 8;
  if (is_bf) {
    for (; i < n; i += stride)
      *(bf16x8*)(dst + i) = *(const bf16x8*)((const short*)src + i);
  } else {
    for (; i < n; i += stride) {
      const float* p = (const float*)src + i;
      bf16x8 r;
#pragma unroll
      for (int j = 0; j < 8; ++j) r[j] = f2bf(p[j]);
      *(bf16x8*)(dst + i) = r;
    }
  }
}

// Pure-bf16 B^T GEMM: C[m,n] = A[m,:].W[n,:] + bias[n]; fp32 acc.
// Software-pipelined staging (loads for kt+1 issued before compute of kt).
__global__ __launch_bounds__(256) void gemm_bt3(
    const short* __restrict__ A,
    const short* __restrict__ W0, const short* __restrict__ W1, const short* __restrict__ W2,
    const void* __restrict__ b0, const void* __restrict__ b1, const void* __restrict__ b2,
    void* __restrict__ C0, void* __restrict__ C1, void* __restrict__ C2,
    const int* __restrict__ flags, int nbn, int store_f32)
{
  constexpr int K = 1024;
  constexpr int N = 1024;
  __shared__ short As[128 * 32];
  __shared__ short Bs[128 * 32];

  const int t = threadIdx.x;
  const int w = t >> 6, lane = t & 63;
  const int l15 = lane & 15, quad = lane >> 4;
  const int wm = w >> 1, wn = w & 1;

  const int is_bf = flags[0];
  const int bx = blockIdx.x;
  const int mat = bx / nbn;
  const int n0 = (bx % nbn) * 128;
  const int m0 = blockIdx.y * 128;

  const short* W  = (mat == 0) ? W0 : (mat == 1 ? W1 : W2);
  const void* bia = (mat == 0) ? b0 : (mat == 1 ? b1 : b2);
  void*       C   = (mat == 0) ? C0 : (mat == 1 ? C1 : C2);

  f32x4 acc[4][4];
  for (int mi = 0; mi < 4; ++mi)
    for (int ni = 0; ni < 4; ++ni)
      for (int r = 0; r < 4; ++r) acc[mi][ni][r] = 0.f;

  const int srow = t >> 2;
  const int sch  = (t & 3) * 8;
  const short* Ap = A + (long)(m0 + srow) * K + sch;
  const short* Wp = W + (long)(n0 + srow) * K + sch;

  bf16x8 ra0 = *(const bf16x8*)(Ap);
  bf16x8 ra1 = *(const bf16x8*)(Ap + 64L * K);
  bf16x8 rb0 = *(const bf16x8*)(Wp);
  bf16x8 rb1 = *(const bf16x8*)(Wp + 64L * K);

  for (int kt = 0; kt < K / 32; ++kt) {
    __syncthreads();
    *(bf16x8*)&As[(srow)      * 32 + sch] = ra0;
    *(bf16x8*)&As[(srow + 64) * 32 + sch] = ra1;
    *(bf16x8*)&Bs[(srow)      * 32 + sch] = rb0;
    *(bf16x8*)&Bs[(srow + 64) * 32 + sch] = rb1;
    __syncthreads();
    if (kt + 1 < K / 32) {                       // prefetch next tile (in flight during MFMA)
      ra0 = *(const bf16x8*)(Ap + (kt + 1) * 32);
      ra1 = *(const bf16x8*)(Ap + (kt + 1) * 32 + 64L * K);
      rb0 = *(const bf16x8*)(Wp + (kt + 1) * 32);
      rb1 = *(const bf16x8*)(Wp + (kt + 1) * 32 + 64L * K);
    }
    bf16x8 af[4], bfr[4];
    for (int mi = 0; mi < 4; ++mi)
      af[mi] = *(const bf16x8*)&As[(wm * 64 + mi * 16 + l15) * 32 + quad * 8];
    for (int ni = 0; ni < 4; ++ni)
      bfr[ni] = *(const bf16x8*)&Bs[(wn * 64 + ni * 16 + l15) * 32 + quad * 8];
    for (int mi = 0; mi < 4; ++mi)
      for (int ni = 0; ni < 4; ++ni)
        acc[mi][ni] = __builtin_amdgcn_mfma_f32_16x16x32_bf16(af[mi], bfr[ni], acc[mi][ni], 0, 0, 0);
  }

  for (int ni = 0; ni < 4; ++ni) {
    const int col = n0 + wn * 64 + ni * 16 + l15;
    const float bv = loadf(bia, col, is_bf);
    for (int mi = 0; mi < 4; ++mi) {
      const int row = m0 + wm * 64 + mi * 16 + quad * 4;
      for (int r = 0; r < 4; ++r) {
        const float v = acc[mi][ni][r] + bv;
        const long idx = (long)(row + r) * N + col;
        if (store_f32) ((float*)C)[idx] = v;
        else           ((short*)C)[idx] = f2bf(v);
      }
    }
  }
}

// Flash attention, causal, modality bias.
// Load-balanced: block p handles q-strips p and 31-p sequentially (33 k-tiles const).
// Pipelined K/V staging; P round-trip uses wave-local lgkmcnt wait, not a barrier.
__global__ __launch_bounds__(256) void attn_kernel(
    const short* __restrict__ Q, const short* __restrict__ Kg, const short* __restrict__ Vg,
    const int* __restrict__ mod, const void* __restrict__ cmw,
    const int* __restrict__ flags, short* __restrict__ CTX)
{
  __shared__ short Ks[64 * 80];
  __shared__ short Vt[64 * 80];
  __shared__ short Ps[4 * 16 * 80];
  __shared__ float cm[9];
  __shared__ int mods[2048];

  const int t = threadIdx.x;
  const int w = t >> 6, lane = t & 63;
  const int l15 = lane & 15, quad = lane >> 4;
  const int h = blockIdx.y;
  const int m64 = flags[1];

  if (t < 9) cm[t] = loadf(cmw, t, flags[0]);
  for (int i = t; i < 2048; i += 256) mods[i] = mod[i << m64];
  __syncthreads();

  const int krow = t >> 3, kch = (t & 7) * 8;   // K staging map (rows 0..31 / +32)
  const int vkp = t & 63, vdc = (t >> 6) * 8;   // V staging map

  for (int half = 0; half < 2; ++half) {
    const int strip = (half == 0) ? (int)blockIdx.x : 31 - (int)blockIdx.x;
    const int q0 = strip * 64;
    const int nkt = strip + 1;

    const short* qb = Q + (long)(q0 + w * 16 + l15) * HID + h * 64 + quad * 8;
    const bf16x8 aq0 = *(const bf16x8*)qb;
    const bf16x8 aq1 = *(const bf16x8*)(qb + 32);

    int mrow[4];
    for (int r = 0; r < 4; ++r) mrow[r] = mods[q0 + w * 16 + quad * 4 + r];

    float m_i[4], l_i[4];
    f32x4 acc_o[4];
    for (int r = 0; r < 4; ++r) { m_i[r] = -1e30f; l_i[r] = 0.f; }
    for (int ni = 0; ni < 4; ++ni)
      for (int r = 0; r < 4; ++r) acc_o[ni][r] = 0.f;

    // preload tile 0
    bf16x8 rk0 = *(const bf16x8*)(Kg + (long)krow * HID + h * 64 + kch);
    bf16x8 rk1 = *(const bf16x8*)(Kg + (long)(krow + 32) * HID + h * 64 + kch);
    bf16x8 rv0 = *(const bf16x8*)(Vg + (long)vkp * HID + h * 64 + vdc);
    bf16x8 rv1 = *(const bf16x8*)(Vg + (long)vkp * HID + h * 64 + 32 + vdc);

    for (int kt = 0; kt < nkt; ++kt) {
      __syncthreads();  // prior compute done with Ks/Vt
      *(bf16x8*)&Ks[krow * 80 + kch] = rk0;
      *(bf16x8*)&Ks[(krow + 32) * 80 + kch] = rk1;
#pragma unroll
      for (int j = 0; j < 8; ++j) Vt[(vdc + j) * 80 + vkp] = rv0[j];
#pragma unroll
      for (int j = 0; j < 8; ++j) Vt[(vdc + 32 + j) * 80 + vkp] = rv1[j];
      __syncthreads();
      if (kt + 1 < nkt) {  // prefetch next K/V tile during compute
        const long kb = (long)((kt + 1) * 64) * HID + h * 64;
        rk0 = *(const bf16x8*)(Kg + kb + (long)krow * HID + kch);
        rk1 = *(const bf16x8*)(Kg + kb + (long)(krow + 32) * HID + kch);
        rv0 = *(const bf16x8*)(Vg + kb + (long)vkp * HID + vdc);
        rv1 = *(const bf16x8*)(Vg + kb + (long)vkp * HID + 32 + vdc);
      }

      // S = Q K^T (16x64 per wave)
      f32x4 sc[4];
      for (int nt = 0; nt < 4; ++nt) {
        const bf16x8 kb0 = *(const bf16x8*)&Ks[(nt * 16 + l15) * 80 + quad * 8];
        const bf16x8 kb1 = *(const bf16x8*)&Ks[(nt * 16 + l15) * 80 + 32 + quad * 8];
        f32x4 z;
        for (int r = 0; r < 4; ++r) z[r] = 0.f;
        z = __builtin_amdgcn_mfma_f32_16x16x32_bf16(aq0, kb0, z, 0, 0, 0);
        z = __builtin_amdgcn_mfma_f32_16x16x32_bf16(aq1, kb1, z, 0, 0, 0);
        sc[nt] = z;
      }

      float sv[4][4], rmax[4];
      for (int r = 0; r < 4; ++r) rmax[r] = -1e30f;
      for (int nt = 0; nt < 4; ++nt) {
        const int mcol = mods[kt * 64 + nt * 16 + l15];
        for (int r = 0; r < 4; ++r) {
          float x = sc[nt][r] * 0.125f + cm[mrow[r] * 3 + mcol];
          sv[nt][r] = x;
          rmax[r] = fmaxf(rmax[r], x);
        }
      }
      if (kt == nkt - 1) {  // diagonal tile: apply causal mask
        for (int r = 0; r < 4; ++r) rmax[r] = -1e30f;
        for (int nt = 0; nt < 4; ++nt) {
          const int col = kt * 64 + nt * 16 + l15;
          for (int r = 0; r < 4; ++r) {
            const int row = q0 + w * 16 + quad * 4 + r;
            sv[nt][r] = (col <= row) ? sv[nt][r] : -1e30f;
            rmax[r] = fmaxf(rmax[r], sv[nt][r]);
          }
        }
      }
      for (int off = 1; off < 16; off <<= 1)
        for (int r = 0; r < 4; ++r) rmax[r] = fmaxf(rmax[r], __shfl_xor(rmax[r], off));

      float alpha[4], rsum[4];
      for (int r = 0; r < 4; ++r) {
        const float mn = fmaxf(m_i[r], rmax[r]);
        alpha[r] = __expf(m_i[r] - mn);
        m_i[r] = mn;
        rsum[r] = 0.f;
      }
      short pb[4][4];
      for (int nt = 0; nt < 4; ++nt)
        for (int r = 0; r < 4; ++r) {
          const float p = __expf(sv[nt][r] - m_i[r]);
          rsum[r] += p;
          pb[nt][r] = f2bf(p);
        }
      for (int off = 1; off < 16; off <<= 1)
        for (int r = 0; r < 4; ++r) rsum[r] += __shfl_xor(rsum[r], off);
      for (int r = 0; r < 4; ++r) l_i[r] = l_i[r] * alpha[r] + rsum[r];
      for (int ni = 0; ni < 4; ++ni)
        for (int r = 0; r < 4; ++r) acc_o[ni][r] *= alpha[r];

      // P: C-layout -> A-layout via per-wave LDS strip (wave-local round-trip)
      short* Pw = &Ps[w * 16 * 80];
      for (int nt = 0; nt < 4; ++nt)
        for (int r = 0; r < 4; ++r)
          Pw[(quad * 4 + r) * 80 + nt * 16 + l15] = pb[nt][r];
      asm volatile("s_waitcnt lgkmcnt(0)" ::: "memory");  // wave-local ds RAW drain

      for (int kk = 0; kk < 2; ++kk) {
        const bf16x8 ap = *(const bf16x8*)&Pw[l15 * 80 + kk * 32 + quad * 8];
        for (int ni = 0; ni < 4; ++ni) {
          const bf16x8 bv = *(const bf16x8*)&Vt[(ni * 16 + l15) * 80 + kk * 32 + quad * 8];
          acc_o[ni] = __builtin_amdgcn_mfma_f32_16x16x32_bf16(ap, bv, acc_o[ni], 0, 0, 0);
        }
      }
    }

    for (int ni = 0; ni < 4; ++ni) {
      const int col = h * 64 + ni * 16 + l15;
      for (int r = 0; r < 4; ++r) {
        const int row = q0 + w * 16 + quad * 4 + r;
        CTX[(long)row * HID + col] = f2bf(acc_o[ni][r] / l_i[r]);
      }
    }
  }
}

extern "C" void kernel_launch(void* const* d_in, const int* in_sizes, int n_in,
                              void* d_out, int out_size, void* d_ws, size_t ws_size,
                              hipStream_t stream) {
  constexpr long M1 = 1024L * 1024L;
  int*   flags = (int*)d_ws;
  short* base  = (short*)d_ws + 128;
  short* xb  = base;            // 2M shorts (4MB)
  short* Wqb = xb + 2 * M1;     // 1M shorts each
  short* Wkb = Wqb + M1;
  short* Wvb = Wkb + M1;
  short* Wob = Wvb + M1;
  short* Qw  = Wob + M1;        // 2M shorts each
  short* Kw  = Qw + 2 * M1;
  short* Vw  = Kw + 2 * M1;
  short* CTX = Vw + 2 * M1;     // total ws: ~28MB + 256B
  const int* modality = (const int*)d_in[11];

  detect_kernel<<<1, 64, 0, stream>>>((const unsigned*)d_in[0], modality, flags);
  convert5<<<dim3(512, 5), 256, 0, stream>>>(
      d_in[0], d_in[1], d_in[3], d_in[5], d_in[7],
      xb, Wqb, Wkb, Wvb, Wob, flags);

  // QKV projection (pure-bf16 MFMA)
  gemm_bt3<<<dim3(24, 16), 256, 0, stream>>>(
      xb, Wqb, Wkb, Wvb, d_in[2], d_in[4], d_in[6],
      Qw, Kw, Vw, flags, 8, /*store_f32=*/0);
  // attention (balanced flash): 16 strip-pairs x 16 heads
  attn_kernel<<<dim3(16, NHEAD), 256, 0, stream>>>(Qw, Kw, Vw, modality, d_in[9], flags, CTX);
  // output projection -> fp32 d_out
  gemm_bt3<<<dim3(8, 16), 256, 0, stream>>>(
      CTX, Wob, Wob, Wob, d_in[8], d_in[8], d_in[8],
      d_out, d_out, d_out, flags, 8, /*store_f32=*/1);
}

// Round 10
// 190.413 us; speedup vs baseline: 1.5397x; 1.0861x over previous
//
#include <hip/hip_runtime.h>
#include <hip/hip_bf16.h>
#include <math.h>

#define S_LEN 2048
#define HID   1024
#define NHEAD 16

using bf16x8 = __attribute__((ext_vector_type(8))) short;
using bf16x4 = __attribute__((ext_vector_type(4))) short;
using f32x4  = __attribute__((ext_vector_type(4))) float;

__device__ __forceinline__ float bf2f(short s) {
  union { unsigned u; float f; } c;
  c.u = ((unsigned)(unsigned short)s) << 16;
  return c.f;
}
__device__ __forceinline__ short f2bf(float f) {
  union { float f; unsigned u; } c; c.f = f;
  unsigned u = c.u;
  unsigned r = (u + 0x7fffu + ((u >> 16) & 1u)) >> 16;
  return (short)r;
}
__device__ __forceinline__ float loadf(const void* base, long idx, int is_bf) {
  return is_bf ? bf2f(((const short*)base)[idx]) : ((const float*)base)[idx];
}

// flags[0]=1 iff float arrays are packed bf16; 0 if fp32 storage.
// flags[1]=1 iff modality_info is int64.
__global__ void detect_kernel(const unsigned* __restrict__ xw,
                              const int* __restrict__ modw,
                              int* __restrict__ flags) {
  const int t = threadIdx.x;  // 64 threads
  int cnt = 0;
  for (int i = t; i < 1024; i += 64) {
    const unsigned fld = (xw[i] >> 7) & 0xFFu;
    cnt += (fld >= 100u && fld <= 135u) ? 1 : 0;
  }
  int odd = 0;
  for (int i = 0; i < 4; ++i) {
    const int wv = modw[2 * (t + 64 * i) + 1];
    odd += (wv != 0) ? 1 : 0;
  }
  for (int m = 1; m < 64; m <<= 1) {
    cnt += __shfl_xor(cnt, m);
    odd += __shfl_xor(odd, m);
  }
  if (t == 0) {
    flags[0] = (cnt >= 512) ? 1 : 0;
    flags[1] = (odd == 0) ? 1 : 0;
  }
}

// Convert x + 4 weights to bf16 (or copy). blockIdx.y: 0=x (2M), 1..4=W (1M each).
__global__ __launch_bounds__(256) void convert5(
    const void* __restrict__ s0, const void* __restrict__ s1, const void* __restrict__ s2,
    const void* __restrict__ s3, const void* __restrict__ s4,
    short* __restrict__ d0, short* __restrict__ d1, short* __restrict__ d2,
    short* __restrict__ d3, short* __restrict__ d4,
    const int* __restrict__ flags) {
  const int a = blockIdx.y;
  const void* src = (a == 0) ? s0 : (a == 1) ? s1 : (a == 2) ? s2 : (a == 3) ? s3 : s4;
  short* dst = (a == 0) ? d0 : (a == 1) ? d1 : (a == 2) ? d2 : (a == 3) ? d3 : d4;
  const long n = (a == 0) ? (2L << 20) : (1L << 20);
  const int is_bf = flags[0];
  long i = (long)(blockIdx.x * 256 + threadIdx.x) * 8;
  const long stride = (long)gridDim.x * 256 * 8;
  if (is_bf) {
    for (; i < n; i += stride)
      *(bf16x8*)(dst + i) = *(const bf16x8*)((const short*)src + i);
  } else {
    for (; i < n; i += stride) {
      const float* p = (const float*)src + i;
      bf16x8 r;
#pragma unroll
      for (int j = 0; j < 8; ++j) r[j] = f2bf(p[j]);
      *(bf16x8*)(dst + i) = r;
    }
  }
}

// Pure-bf16 B^T GEMM, BM=128 BN=64: C[m,n] = A[m,:].W[n,:] + bias[n]; fp32 acc.
// 4 waves: wm=w>>1 (64 rows), wn=w&1 (32 cols); 4x2 MFMA acc. Prefetch-pipelined.
__global__ __launch_bounds__(256) void gemm_bt3(
    const short* __restrict__ A,
    const short* __restrict__ W0, const short* __restrict__ W1, const short* __restrict__ W2,
    const void* __restrict__ b0, const void* __restrict__ b1, const void* __restrict__ b2,
    void* __restrict__ C0, void* __restrict__ C1, void* __restrict__ C2,
    const int* __restrict__ flags, int nbn, int store_f32)
{
  constexpr int K = 1024;
  constexpr int N = 1024;
  __shared__ short As[128 * 32];
  __shared__ short Bs[64 * 32];

  const int t = threadIdx.x;
  const int w = t >> 6, lane = t & 63;
  const int l15 = lane & 15, quad = lane >> 4;
  const int wm = w >> 1, wn = w & 1;

  const int is_bf = flags[0];
  const int bx = blockIdx.x;
  const int mat = bx / nbn;
  const int n0 = (bx % nbn) * 64;
  const int m0 = blockIdx.y * 128;

  const short* W  = (mat == 0) ? W0 : (mat == 1 ? W1 : W2);
  const void* bia = (mat == 0) ? b0 : (mat == 1 ? b1 : b2);
  void*       C   = (mat == 0) ? C0 : (mat == 1 ? C1 : C2);

  f32x4 acc[4][2];
  for (int mi = 0; mi < 4; ++mi)
    for (int ni = 0; ni < 2; ++ni)
      for (int r = 0; r < 4; ++r) acc[mi][ni][r] = 0.f;

  const int srow = t >> 2;        // 0..63
  const int sch  = (t & 3) * 8;
  const short* Ap = A + (long)(m0 + srow) * K + sch;
  const short* Wp = W + (long)(n0 + srow) * K + sch;

  bf16x8 ra0 = *(const bf16x8*)(Ap);
  bf16x8 ra1 = *(const bf16x8*)(Ap + 64L * K);
  bf16x8 rb0 = *(const bf16x8*)(Wp);

  for (int kt = 0; kt < K / 32; ++kt) {
    __syncthreads();
    *(bf16x8*)&As[(srow)      * 32 + sch] = ra0;
    *(bf16x8*)&As[(srow + 64) * 32 + sch] = ra1;
    *(bf16x8*)&Bs[(srow)      * 32 + sch] = rb0;
    __syncthreads();
    if (kt + 1 < K / 32) {
      ra0 = *(const bf16x8*)(Ap + (kt + 1) * 32);
      ra1 = *(const bf16x8*)(Ap + (kt + 1) * 32 + 64L * K);
      rb0 = *(const bf16x8*)(Wp + (kt + 1) * 32);
    }
    bf16x8 af[4], bfr[2];
    for (int mi = 0; mi < 4; ++mi)
      af[mi] = *(const bf16x8*)&As[(wm * 64 + mi * 16 + l15) * 32 + quad * 8];
    for (int ni = 0; ni < 2; ++ni)
      bfr[ni] = *(const bf16x8*)&Bs[(wn * 32 + ni * 16 + l15) * 32 + quad * 8];
    for (int mi = 0; mi < 4; ++mi)
      for (int ni = 0; ni < 2; ++ni)
        acc[mi][ni] = __builtin_amdgcn_mfma_f32_16x16x32_bf16(af[mi], bfr[ni], acc[mi][ni], 0, 0, 0);
  }

  for (int ni = 0; ni < 2; ++ni) {
    const int col = n0 + wn * 32 + ni * 16 + l15;
    const float bv = loadf(bia, col, is_bf);
    for (int mi = 0; mi < 4; ++mi) {
      const int row = m0 + wm * 64 + mi * 16 + quad * 4;
      for (int r = 0; r < 4; ++r) {
        const float v = acc[mi][ni][r] + bv;
        const long idx = (long)(row + r) * N + col;
        if (store_f32) ((float*)C)[idx] = v;
        else           ((short*)C)[idx] = f2bf(v);
      }
    }
  }
}

// Split-K flash attention. blockIdx.x in [0,32): pair=x>>1, par=x&1; blockIdx.y=head.
// Block handles strips {pair, 31-pair} sequentially, k-tiles of its parity only
// (~17 tiles). Stores UNNORMALIZED partials (O bf16, m/l fp32) for attn_merge.
__global__ __launch_bounds__(256) void attn_split(
    const short* __restrict__ Q, const short* __restrict__ Kg, const short* __restrict__ Vg,
    const int* __restrict__ mod, const void* __restrict__ cmw,
    const int* __restrict__ flags,
    short* __restrict__ PO, float* __restrict__ PM, float* __restrict__ PL)
{
  __shared__ short Ks[64 * 80];
  __shared__ short Vt[64 * 80];
  __shared__ short Ps[4 * 16 * 80];
  __shared__ float cm[9];
  __shared__ int mods[2048];

  const int t = threadIdx.x;
  const int w = t >> 6, lane = t & 63;
  const int l15 = lane & 15, quad = lane >> 4;
  const int h = blockIdx.y;
  const int pair = blockIdx.x >> 1;
  const int par  = blockIdx.x & 1;
  const int m64 = flags[1];

  if (t < 9) cm[t] = loadf(cmw, t, flags[0]);
  for (int i = t; i < 2048; i += 256) mods[i] = mod[i << m64];
  __syncthreads();

  const int krow = t >> 3, kch = (t & 7) * 8;
  const int vkp = t & 63, vdc = (t >> 6) * 8;

  for (int si = 0; si < 2; ++si) {
    const int strip = (si == 0) ? pair : 31 - pair;
    const int q0 = strip * 64;
    const int nkt = strip + 1;

    const short* qb = Q + (long)(q0 + w * 16 + l15) * HID + h * 64 + quad * 8;
    const bf16x8 aq0 = *(const bf16x8*)qb;
    const bf16x8 aq1 = *(const bf16x8*)(qb + 32);

    int mrow[4];
    for (int r = 0; r < 4; ++r) mrow[r] = mods[q0 + w * 16 + quad * 4 + r];

    float m_i[4], l_i[4];
    f32x4 acc_o[4];
    for (int r = 0; r < 4; ++r) { m_i[r] = -1e30f; l_i[r] = 0.f; }
    for (int ni = 0; ni < 4; ++ni)
      for (int r = 0; r < 4; ++r) acc_o[ni][r] = 0.f;

    bf16x8 rk0, rk1, rv0, rv1;
    if (par < nkt) {  // preload first tile of this parity
      const long kb = (long)(par * 64) * HID + h * 64;
      rk0 = *(const bf16x8*)(Kg + kb + (long)krow * HID + kch);
      rk1 = *(const bf16x8*)(Kg + kb + (long)(krow + 32) * HID + kch);
      rv0 = *(const bf16x8*)(Vg + kb + (long)vkp * HID + vdc);
      rv1 = *(const bf16x8*)(Vg + kb + (long)vkp * HID + 32 + vdc);
    }

    for (int kt = par; kt < nkt; kt += 2) {
      __syncthreads();
      *(bf16x8*)&Ks[krow * 80 + kch] = rk0;
      *(bf16x8*)&Ks[(krow + 32) * 80 + kch] = rk1;
#pragma unroll
      for (int j = 0; j < 8; ++j) Vt[(vdc + j) * 80 + vkp] = rv0[j];
#pragma unroll
      for (int j = 0; j < 8; ++j) Vt[(vdc + 32 + j) * 80 + vkp] = rv1[j];
      __syncthreads();
      if (kt + 2 < nkt) {
        const long kb = (long)((kt + 2) * 64) * HID + h * 64;
        rk0 = *(const bf16x8*)(Kg + kb + (long)krow * HID + kch);
        rk1 = *(const bf16x8*)(Kg + kb + (long)(krow + 32) * HID + kch);
        rv0 = *(const bf16x8*)(Vg + kb + (long)vkp * HID + vdc);
        rv1 = *(const bf16x8*)(Vg + kb + (long)vkp * HID + 32 + vdc);
      }

      f32x4 sc[4];
      for (int nt = 0; nt < 4; ++nt) {
        const bf16x8 kb0 = *(const bf16x8*)&Ks[(nt * 16 + l15) * 80 + quad * 8];
        const bf16x8 kb1 = *(const bf16x8*)&Ks[(nt * 16 + l15) * 80 + 32 + quad * 8];
        f32x4 z;
        for (int r = 0; r < 4; ++r) z[r] = 0.f;
        z = __builtin_amdgcn_mfma_f32_16x16x32_bf16(aq0, kb0, z, 0, 0, 0);
        z = __builtin_amdgcn_mfma_f32_16x16x32_bf16(aq1, kb1, z, 0, 0, 0);
        sc[nt] = z;
      }

      float sv[4][4], rmax[4];
      for (int r = 0; r < 4; ++r) rmax[r] = -1e30f;
      for (int nt = 0; nt < 4; ++nt) {
        const int mcol = mods[kt * 64 + nt * 16 + l15];
        for (int r = 0; r < 4; ++r) {
          float x = sc[nt][r] * 0.125f + cm[mrow[r] * 3 + mcol];
          sv[nt][r] = x;
          rmax[r] = fmaxf(rmax[r], x);
        }
      }
      if (kt == nkt - 1) {  // diagonal tile: causal mask
        for (int r = 0; r < 4; ++r) rmax[r] = -1e30f;
        for (int nt = 0; nt < 4; ++nt) {
          const int col = kt * 64 + nt * 16 + l15;
          for (int r = 0; r < 4; ++r) {
            const int row = q0 + w * 16 + quad * 4 + r;
            sv[nt][r] = (col <= row) ? sv[nt][r] : -1e30f;
            rmax[r] = fmaxf(rmax[r], sv[nt][r]);
          }
        }
      }
      for (int off = 1; off < 16; off <<= 1)
        for (int r = 0; r < 4; ++r) rmax[r] = fmaxf(rmax[r], __shfl_xor(rmax[r], off));

      float alpha[4], rsum[4];
      for (int r = 0; r < 4; ++r) {
        const float mn = fmaxf(m_i[r], rmax[r]);
        alpha[r] = __expf(m_i[r] - mn);
        m_i[r] = mn;
        rsum[r] = 0.f;
      }
      short pb[4][4];
      for (int nt = 0; nt < 4; ++nt)
        for (int r = 0; r < 4; ++r) {
          const float p = __expf(sv[nt][r] - m_i[r]);
          rsum[r] += p;
          pb[nt][r] = f2bf(p);
        }
      for (int off = 1; off < 16; off <<= 1)
        for (int r = 0; r < 4; ++r) rsum[r] += __shfl_xor(rsum[r], off);
      for (int r = 0; r < 4; ++r) l_i[r] = l_i[r] * alpha[r] + rsum[r];
      for (int ni = 0; ni < 4; ++ni)
        for (int r = 0; r < 4; ++r) acc_o[ni][r] *= alpha[r];

      short* Pw = &Ps[w * 16 * 80];
      for (int nt = 0; nt < 4; ++nt)
        for (int r = 0; r < 4; ++r)
          Pw[(quad * 4 + r) * 80 + nt * 16 + l15] = pb[nt][r];
      asm volatile("s_waitcnt lgkmcnt(0)" ::: "memory");  // wave-local ds RAW drain

      for (int kk = 0; kk < 2; ++kk) {
        const bf16x8 ap = *(const bf16x8*)&Pw[l15 * 80 + kk * 32 + quad * 8];
        for (int ni = 0; ni < 4; ++ni) {
          const bf16x8 bv = *(const bf16x8*)&Vt[(ni * 16 + l15) * 80 + kk * 32 + quad * 8];
          acc_o[ni] = __builtin_amdgcn_mfma_f32_16x16x32_bf16(ap, bv, acc_o[ni], 0, 0, 0);
        }
      }
    }

    // store unnormalized partials
    const long pbase = (long)par * 2097152;
    for (int ni = 0; ni < 4; ++ni) {
      const int col = h * 64 + ni * 16 + l15;
      for (int r = 0; r < 4; ++r) {
        const int row = q0 + w * 16 + quad * 4 + r;
        PO[pbase + (long)row * HID + col] = f2bf(acc_o[ni][r]);
      }
    }
    if (l15 == 0) {
      for (int r = 0; r < 4; ++r) {
        const int row = q0 + w * 16 + quad * 4 + r;
        PM[par * 32768 + row * 16 + h] = m_i[r];
        PL[par * 32768 + row * 16 + h] = l_i[r];
      }
    }
  }
}

// Merge the two parity partials -> CTX (bf16). block=row, thread t: h=t>>4, d=(t&15)*4.
__global__ __launch_bounds__(256) void attn_merge(
    const short* __restrict__ PO, const float* __restrict__ PM, const float* __restrict__ PL,
    short* __restrict__ CTX)
{
  const int row = blockIdx.x;
  const int t = threadIdx.x;
  const int h = t >> 4;
  const int d0 = (t & 15) * 4;
  const float m0 = PM[row * 16 + h], m1 = PM[32768 + row * 16 + h];
  const float l0 = PL[row * 16 + h], l1 = PL[32768 + row * 16 + h];
  const float M = fmaxf(m0, m1);
  const float w0 = __expf(m0 - M), w1 = __expf(m1 - M);
  const float inv = 1.f / (l0 * w0 + l1 * w1);
  const long b = (long)row * HID + h * 64 + d0;
  const bf16x4 o0 = *(const bf16x4*)&PO[b];
  const bf16x4 o1 = *(const bf16x4*)&PO[2097152 + b];
  bf16x4 out;
#pragma unroll
  for (int j = 0; j < 4; ++j)
    out[j] = f2bf((bf2f(o0[j]) * w0 + bf2f(o1[j]) * w1) * inv);
  *(bf16x4*)&CTX[b] = out;
}

extern "C" void kernel_launch(void* const* d_in, const int* in_sizes, int n_in,
                              void* d_out, int out_size, void* d_ws, size_t ws_size,
                              hipStream_t stream) {
  constexpr long M1 = 1024L * 1024L;
  int*   flags = (int*)d_ws;
  short* base  = (short*)d_ws + 128;
  short* xb  = base;            // 2M shorts (4MB)
  short* Wqb = xb + 2 * M1;     // 1M shorts each
  short* Wkb = Wqb + M1;
  short* Wvb = Wkb + M1;
  short* Wob = Wvb + M1;
  short* Qw  = Wob + M1;        // 2M shorts each
  short* Kw  = Qw + 2 * M1;
  short* Vw  = Kw + 2 * M1;
  short* CTX = Vw + 2 * M1;     // total ws: 28MB + 256B
  // partial buffers ALIAS dead regions (xb/Wqb/Wkb dead after QKV gemm; Wvb after too)
  short* PO = xb;               // 4M shorts = 8MB (xb+Wqb+Wkb exactly)
  float* PM = (float*)Wvb;      // 64K floats = 256KB
  float* PL = PM + 65536;       // 256KB more (within Wvb's 2MB)
  const int* modality = (const int*)d_in[11];

  detect_kernel<<<1, 64, 0, stream>>>((const unsigned*)d_in[0], modality, flags);
  convert5<<<dim3(512, 5), 256, 0, stream>>>(
      d_in[0], d_in[1], d_in[3], d_in[5], d_in[7],
      xb, Wqb, Wkb, Wvb, Wob, flags);

  // QKV projection: 3 mats x 16 n-tiles x 16 m-tiles = 768 blocks
  gemm_bt3<<<dim3(48, 16), 256, 0, stream>>>(
      xb, Wqb, Wkb, Wvb, d_in[2], d_in[4], d_in[6],
      Qw, Kw, Vw, flags, 16, /*store_f32=*/0);
  // attention split-K: 16 pairs x 2 parities x 16 heads = 512 blocks
  attn_split<<<dim3(32, NHEAD), 256, 0, stream>>>(
      Qw, Kw, Vw, modality, d_in[9], flags, PO, PM, PL);
  attn_merge<<<dim3(S_LEN), 256, 0, stream>>>(PO, PM, PL, CTX);
  // output projection: 16 x 16 = 256 blocks -> fp32 d_out
  gemm_bt3<<<dim3(16, 16), 256, 0, stream>>>(
      CTX, Wob, Wob, Wob, d_in[8], d_in[8], d_in[8],
      d_out, d_out, d_out, flags, 16, /*store_f32=*/1);
}